// Round 1
// baseline (302.016 us; speedup 1.0000x reference)
//
#include <hip/hip_runtime.h>
#include <math.h>

#define NV 4096      // variable nodes
#define MC 2048      // check nodes
#define DV 3
#define DC 6
#define NE (NV * DV) // 12288 edges
#define NB 2048      // batch
#define NITER 5

// Build per-check-node edge lists (slot order arbitrary due to atomics).
__global__ __launch_bounds__(256) void build_cn(const int* __restrict__ cn_idx,
                                                int* __restrict__ cn_edges,
                                                int* __restrict__ cn_cnt) {
    int e = blockIdx.x * 256 + threadIdx.x;
    if (e < NE) {
        int m = cn_idx[e];
        int slot = atomicAdd(&cn_cnt[m], 1);
        cn_edges[m * DC + slot] = e;
    }
}

// Sort each CN's 6 edges ascending -> deterministic and matches numpy's
// sequential scatter-add order (edge index order).
__global__ __launch_bounds__(256) void sort_cn(int* __restrict__ cn_edges) {
    int m = blockIdx.x * 256 + threadIdx.x;
    if (m < MC) {
        int v[DC];
        for (int j = 0; j < DC; ++j) v[j] = cn_edges[m * DC + j];
        for (int i = 1; i < DC; ++i) {
            int key = v[i]; int j = i - 1;
            while (j >= 0 && v[j] > key) { v[j + 1] = v[j]; --j; }
            v[j + 1] = key;
        }
        for (int j = 0; j < DC; ++j) cn_edges[m * DC + j] = v[j];
    }
}

// One workgroup per batch element; all E messages live in LDS (48 KB).
// msg[] holds WEIGHTED vn->cn messages before CN phase, cn->vn messages after.
__global__ __launch_bounds__(256) void bp_iter(const float* __restrict__ noise_r,
                                               const float* __restrict__ ew,
                                               const int* __restrict__ cn_edges,
                                               float* __restrict__ out) {
    __shared__ float msg[NE];
    const int b = blockIdx.x;
    const int t = threadIdx.x;

    const float NO   = (float)0.3981071705534972;          // 1/(R*2*10^(EbNo/10))
    const float NSTD = sqrtf((float)(0.3981071705534972 * 0.5));
    const float CLIP = (float)(1.0 - 1e-7);

    float llr[NV / 256];
    const float* nb = noise_r + (size_t)b * NV;
#pragma unroll
    for (int k = 0; k < NV / 256; ++k) {
        int n = t + 256 * k;
        float y = 1.0f + NSTD * nb[n];
        float l = (4.0f * y) / NO;
        llr[k] = l;
        msg[3 * n + 0] = l * ew[3 * n + 0];
        msg[3 * n + 1] = l * ew[3 * n + 1];
        msg[3 * n + 2] = l * ew[3 * n + 2];
    }
    __syncthreads();

    for (int it = 0; it < NITER; ++it) {
        // ---- CN update: each thread owns 8 check nodes ----
#pragma unroll
        for (int c = 0; c < MC / 256; ++c) {
            int m = t + 256 * c;
            int   eidx[DC];
            float lt[DC], nmsg[DC];
            int   sg[DC];
            int   cnt = 0;
            float sum = 0.0f;
#pragma unroll
            for (int j = 0; j < DC; ++j) {
                eidx[j] = cn_edges[m * DC + j];
                float mw = msg[eidx[j]];
                float tt = tanhf(0.5f * mw);
                float l  = logf(fabsf(tt) + 1e-12f);
                lt[j] = l;
                sum  += l;                    // ascending-edge order matches np
                sg[j] = (tt < 0.0f) ? 1 : 0;
                cnt  += sg[j];
            }
#pragma unroll
            for (int j = 0; j < DC; ++j) {
                float ex  = sum - lt[j];
                float mag = fminf(expf(ex), CLIP);
                float at  = 0.5f * logf((1.0f + mag) / (1.0f - mag));
                float s   = ((cnt - sg[j]) & 1) ? -2.0f : 2.0f;
                nmsg[j]   = s * at;
            }
#pragma unroll
            for (int j = 0; j < DC; ++j) msg[eidx[j]] = nmsg[j];
        }
        __syncthreads();

        // ---- VN update: each thread owns 16 variable nodes ----
        if (it < NITER - 1) {
#pragma unroll
            for (int k = 0; k < NV / 256; ++k) {
                int n = t + 256 * k;
                float c0 = msg[3 * n + 0];
                float c1 = msg[3 * n + 1];
                float c2 = msg[3 * n + 2];
                float tot = llr[k] + (c0 + c1 + c2);
                msg[3 * n + 0] = (tot - c0) * ew[3 * n + 0];
                msg[3 * n + 1] = (tot - c1) * ew[3 * n + 1];
                msg[3 * n + 2] = (tot - c2) * ew[3 * n + 2];
            }
            __syncthreads();
        } else {
#pragma unroll
            for (int k = 0; k < NV / 256; ++k) {
                int n = t + 256 * k;
                float c0 = msg[3 * n + 0];
                float c1 = msg[3 * n + 1];
                float c2 = msg[3 * n + 2];
                out[(size_t)b * NV + n] = llr[k] + (c0 + c1 + c2);
            }
        }
    }
}

extern "C" void kernel_launch(void* const* d_in, const int* in_sizes, int n_in,
                              void* d_out, int out_size, void* d_ws, size_t ws_size,
                              hipStream_t stream) {
    const float* noise_r = (const float*)d_in[0];
    // d_in[1] = noise_i (unused by reference)
    const float* ew      = (const float*)d_in[2];
    // d_in[3] = vn_idx: known structure e // 3 (edges contiguous per VN)
    const int*   cn_idx  = (const int*)d_in[4];
    float* out = (float*)d_out;

    int* cn_edges = (int*)d_ws;        // NE ints
    int* cn_cnt   = cn_edges + NE;     // MC ints

    hipMemsetAsync(cn_cnt, 0, MC * sizeof(int), stream);
    build_cn<<<(NE + 255) / 256, 256, 0, stream>>>(cn_idx, cn_edges, cn_cnt);
    sort_cn<<<(MC + 255) / 256, 256, 0, stream>>>(cn_edges);
    bp_iter<<<NB, 256, 0, stream>>>(noise_r, ew, cn_edges, out);
}

// Round 2
// 233.830 us; speedup vs baseline: 1.2916x; 1.2916x over previous
//
#include <hip/hip_runtime.h>
#include <math.h>

#define NV 4096      // variable nodes
#define MC 2048      // check nodes
#define DV 3
#define DC 6
#define NE (NV * DV) // 12288 edges
#define NB 2048      // batch
#define NITER 5

// Build per-check-node edge lists (slot order arbitrary due to atomics).
__global__ __launch_bounds__(256) void build_cn(const int* __restrict__ cn_idx,
                                                int* __restrict__ cn_edges,
                                                int* __restrict__ cn_cnt) {
    int e = blockIdx.x * 256 + threadIdx.x;
    if (e < NE) {
        int m = cn_idx[e];
        int slot = atomicAdd(&cn_cnt[m], 1);
        cn_edges[m * DC + slot] = e;
    }
}

// Sort each CN's 6 edges ascending -> deterministic and matches numpy's
// sequential scatter-add order (edge index order).
__global__ __launch_bounds__(256) void sort_cn(int* __restrict__ cn_edges) {
    int m = blockIdx.x * 256 + threadIdx.x;
    if (m < MC) {
        int v[DC];
        for (int j = 0; j < DC; ++j) v[j] = cn_edges[m * DC + j];
        for (int i = 1; i < DC; ++i) {
            int key = v[i]; int j = i - 1;
            while (j >= 0 && v[j] > key) { v[j + 1] = v[j]; --j; }
            v[j + 1] = key;
        }
        for (int j = 0; j < DC; ++j) cn_edges[m * DC + j] = v[j];
    }
}

// One workgroup per batch element; all E messages live in LDS (48 KB).
// msg[] holds WEIGHTED vn->cn messages before CN phase, cn->vn messages after.
__global__ __launch_bounds__(256) void bp_iter(const float* __restrict__ noise_r,
                                               const float* __restrict__ ew,
                                               const int* __restrict__ cn_edges,
                                               float* __restrict__ out) {
    __shared__ float msg[NE];
    const int b = blockIdx.x;
    const int t = threadIdx.x;

    const float NO   = (float)0.3981071705534972;          // 1/(R*2*10^(EbNo/10))
    const float NSTD = sqrtf((float)(0.3981071705534972 * 0.5));
    const float CLIP = (float)(1.0 - 1e-7);

    // Hoist per-CN edge lists into registers (48 VGPR; one-time global read).
    int eidx[MC / 256][DC];
#pragma unroll
    for (int c = 0; c < MC / 256; ++c)
#pragma unroll
        for (int j = 0; j < DC; ++j)
            eidx[c][j] = cn_edges[(t + 256 * c) * DC + j];

    float llr[NV / 256];
    const float* nb = noise_r + (size_t)b * NV;
#pragma unroll
    for (int k = 0; k < NV / 256; ++k) {
        int n = t + 256 * k;
        float y = 1.0f + NSTD * nb[n];
        float l = (4.0f * y) / NO;
        llr[k] = l;
        msg[3 * n + 0] = l * ew[3 * n + 0];
        msg[3 * n + 1] = l * ew[3 * n + 1];
        msg[3 * n + 2] = l * ew[3 * n + 2];
    }
    __syncthreads();

    for (int it = 0; it < NITER; ++it) {
        // ---- CN update: each thread owns 8 check nodes ----
#pragma unroll
        for (int c = 0; c < MC / 256; ++c) {
            float lt[DC], sv[DC];
            float sum = 0.0f, prod = 1.0f;
#pragma unroll
            for (int j = 0; j < DC; ++j) {
                float mw = msg[eidx[c][j]];
                // |tanh(mw/2)| = (1 - e^{-|mw|}) / (1 + e^{-|mw|})
                float u  = __expf(-fabsf(mw));
                float tt = __fdividef(1.0f - u, 1.0f + u);
                float l  = __logf(tt + 1e-12f);
                lt[j] = l;
                sum  += l;                    // ascending-edge order matches np
                float s = (mw < 0.0f) ? -1.0f : 1.0f;
                sv[j] = s;
                prod *= s;
            }
#pragma unroll
            for (int j = 0; j < DC; ++j) {
                float ex  = sum - lt[j];
                float mag = fminf(__expf(ex), CLIP);
                // 2*atanh(m) = ln((1+m)/(1-m))
                float val = __logf(__fdividef(1.0f + mag, 1.0f - mag));
                msg[eidx[c][j]] = (prod * sv[j]) * val;
            }
        }
        __syncthreads();

        // ---- VN update: each thread owns 16 variable nodes ----
        if (it < NITER - 1) {
#pragma unroll
            for (int k = 0; k < NV / 256; ++k) {
                int n = t + 256 * k;
                float c0 = msg[3 * n + 0];
                float c1 = msg[3 * n + 1];
                float c2 = msg[3 * n + 2];
                float tot = llr[k] + (c0 + c1 + c2);
                msg[3 * n + 0] = (tot - c0) * ew[3 * n + 0];
                msg[3 * n + 1] = (tot - c1) * ew[3 * n + 1];
                msg[3 * n + 2] = (tot - c2) * ew[3 * n + 2];
            }
            __syncthreads();
        } else {
#pragma unroll
            for (int k = 0; k < NV / 256; ++k) {
                int n = t + 256 * k;
                float c0 = msg[3 * n + 0];
                float c1 = msg[3 * n + 1];
                float c2 = msg[3 * n + 2];
                out[(size_t)b * NV + n] = llr[k] + (c0 + c1 + c2);
            }
        }
    }
}

extern "C" void kernel_launch(void* const* d_in, const int* in_sizes, int n_in,
                              void* d_out, int out_size, void* d_ws, size_t ws_size,
                              hipStream_t stream) {
    const float* noise_r = (const float*)d_in[0];
    // d_in[1] = noise_i (unused by reference)
    const float* ew      = (const float*)d_in[2];
    // d_in[3] = vn_idx: known structure e // 3 (edges contiguous per VN)
    const int*   cn_idx  = (const int*)d_in[4];
    float* out = (float*)d_out;

    int* cn_edges = (int*)d_ws;        // NE ints
    int* cn_cnt   = cn_edges + NE;     // MC ints

    hipMemsetAsync(cn_cnt, 0, MC * sizeof(int), stream);
    build_cn<<<(NE + 255) / 256, 256, 0, stream>>>(cn_idx, cn_edges, cn_cnt);
    sort_cn<<<(MC + 255) / 256, 256, 0, stream>>>(cn_edges);
    bp_iter<<<NB, 256, 0, stream>>>(noise_r, ew, cn_edges, out);
}

// Round 3
// 218.502 us; speedup vs baseline: 1.3822x; 1.0701x over previous
//
#include <hip/hip_runtime.h>
#include <math.h>

#define NV 4096      // variable nodes
#define MC 2048      // check nodes
#define DV 3
#define DC 6
#define NE (NV * DV) // 12288 edges
#define NB 2048      // batch
#define NITER 5
#define TPB 1024     // 16 waves/block; 2 blocks/CU -> 32 waves/CU (LDS allows 3)

// Build per-check-node edge lists (slot order arbitrary due to atomics).
__global__ __launch_bounds__(256) void build_cn(const int* __restrict__ cn_idx,
                                                int* __restrict__ cn_edges,
                                                int* __restrict__ cn_cnt) {
    int e = blockIdx.x * 256 + threadIdx.x;
    if (e < NE) {
        int m = cn_idx[e];
        int slot = atomicAdd(&cn_cnt[m], 1);
        cn_edges[m * DC + slot] = e;
    }
}

// Sort each CN's 6 edges ascending -> deterministic and matches numpy's
// sequential scatter-add order (edge index order).
__global__ __launch_bounds__(256) void sort_cn(int* __restrict__ cn_edges) {
    int m = blockIdx.x * 256 + threadIdx.x;
    if (m < MC) {
        int v[DC];
        for (int j = 0; j < DC; ++j) v[j] = cn_edges[m * DC + j];
        for (int i = 1; i < DC; ++i) {
            int key = v[i]; int j = i - 1;
            while (j >= 0 && v[j] > key) { v[j + 1] = v[j]; --j; }
            v[j + 1] = key;
        }
        for (int j = 0; j < DC; ++j) cn_edges[m * DC + j] = v[j];
    }
}

// One workgroup per batch element; all E messages live in LDS (48 KB).
// msg[] holds WEIGHTED vn->cn messages before CN phase, cn->vn messages after.
// 1024 threads: each owns 2 CNs and 4 VNs. __launch_bounds__(1024,8) caps
// VGPR at 64 so 2 blocks (32 waves) fit per CU.
__global__ __launch_bounds__(TPB, 8) void bp_iter(const float* __restrict__ noise_r,
                                                  const float* __restrict__ ew,
                                                  const int* __restrict__ cn_edges,
                                                  float* __restrict__ out) {
    __shared__ float msg[NE];
    const int b = blockIdx.x;
    const int t = threadIdx.x;

    const float NO   = (float)0.3981071705534972;          // 1/(R*2*10^(EbNo/10))
    const float NSTD = sqrtf((float)(0.3981071705534972 * 0.5));
    const float CLIP = (float)(1.0 - 1e-7);

    // Hoist per-CN edge lists into registers (12 VGPR; one-time global read).
    int eidx[MC / TPB][DC];
#pragma unroll
    for (int c = 0; c < MC / TPB; ++c)
#pragma unroll
        for (int j = 0; j < DC; ++j)
            eidx[c][j] = cn_edges[(t + TPB * c) * DC + j];

    float llr[NV / TPB];
    const float* nb = noise_r + (size_t)b * NV;
#pragma unroll
    for (int k = 0; k < NV / TPB; ++k) {
        int n = t + TPB * k;
        float y = 1.0f + NSTD * nb[n];
        float l = (4.0f * y) / NO;
        llr[k] = l;
        msg[3 * n + 0] = l * ew[3 * n + 0];
        msg[3 * n + 1] = l * ew[3 * n + 1];
        msg[3 * n + 2] = l * ew[3 * n + 2];
    }
    __syncthreads();

    for (int it = 0; it < NITER; ++it) {
        // ---- CN update: each thread owns 2 check nodes ----
#pragma unroll
        for (int c = 0; c < MC / TPB; ++c) {
            float lt[DC], sv[DC];
            float sum = 0.0f, prod = 1.0f;
#pragma unroll
            for (int j = 0; j < DC; ++j) {
                float mw = msg[eidx[c][j]];
                // |tanh(mw/2)| = (1 - e^{-|mw|}) / (1 + e^{-|mw|})
                float u  = __expf(-fabsf(mw));
                float tt = __fdividef(1.0f - u, 1.0f + u);
                float l  = __logf(tt + 1e-12f);
                lt[j] = l;
                sum  += l;                    // ascending-edge order matches np
                float s = (mw < 0.0f) ? -1.0f : 1.0f;
                sv[j] = s;
                prod *= s;
            }
#pragma unroll
            for (int j = 0; j < DC; ++j) {
                float ex  = sum - lt[j];
                float mag = fminf(__expf(ex), CLIP);
                // 2*atanh(m) = ln((1+m)/(1-m))
                float val = __logf(__fdividef(1.0f + mag, 1.0f - mag));
                msg[eidx[c][j]] = (prod * sv[j]) * val;
            }
        }
        __syncthreads();

        // ---- VN update: each thread owns 4 variable nodes ----
        if (it < NITER - 1) {
#pragma unroll
            for (int k = 0; k < NV / TPB; ++k) {
                int n = t + TPB * k;
                float c0 = msg[3 * n + 0];
                float c1 = msg[3 * n + 1];
                float c2 = msg[3 * n + 2];
                float tot = llr[k] + (c0 + c1 + c2);
                msg[3 * n + 0] = (tot - c0) * ew[3 * n + 0];
                msg[3 * n + 1] = (tot - c1) * ew[3 * n + 1];
                msg[3 * n + 2] = (tot - c2) * ew[3 * n + 2];
            }
            __syncthreads();
        } else {
#pragma unroll
            for (int k = 0; k < NV / TPB; ++k) {
                int n = t + TPB * k;
                float c0 = msg[3 * n + 0];
                float c1 = msg[3 * n + 1];
                float c2 = msg[3 * n + 2];
                out[(size_t)b * NV + n] = llr[k] + (c0 + c1 + c2);
            }
        }
    }
}

extern "C" void kernel_launch(void* const* d_in, const int* in_sizes, int n_in,
                              void* d_out, int out_size, void* d_ws, size_t ws_size,
                              hipStream_t stream) {
    const float* noise_r = (const float*)d_in[0];
    // d_in[1] = noise_i (unused by reference)
    const float* ew      = (const float*)d_in[2];
    // d_in[3] = vn_idx: known structure e // 3 (edges contiguous per VN)
    const int*   cn_idx  = (const int*)d_in[4];
    float* out = (float*)d_out;

    int* cn_edges = (int*)d_ws;        // NE ints
    int* cn_cnt   = cn_edges + NE;     // MC ints

    hipMemsetAsync(cn_cnt, 0, MC * sizeof(int), stream);
    build_cn<<<(NE + 255) / 256, 256, 0, stream>>>(cn_idx, cn_edges, cn_cnt);
    sort_cn<<<(MC + 255) / 256, 256, 0, stream>>>(cn_edges);
    bp_iter<<<NB, TPB, 0, stream>>>(noise_r, ew, cn_edges, out);
}

// Round 4
// 173.002 us; speedup vs baseline: 1.7457x; 1.2630x over previous
//
#include <hip/hip_runtime.h>
#include <math.h>

#define NV 4096      // variable nodes
#define MC 2048      // check nodes
#define DV 3
#define DC 6
#define NE (NV * DV) // 12288 edges
#define NB 2048      // batch
#define NITER 5
#define TPB 1024     // 16 waves/block; 2 blocks/CU -> 32 waves/CU

// Build per-check-node edge lists (slot order arbitrary due to atomics).
__global__ __launch_bounds__(256) void build_cn(const int* __restrict__ cn_idx,
                                                int* __restrict__ cn_edges,
                                                int* __restrict__ cn_cnt) {
    int e = blockIdx.x * 256 + threadIdx.x;
    if (e < NE) {
        int m = cn_idx[e];
        int slot = atomicAdd(&cn_cnt[m], 1);
        cn_edges[m * DC + slot] = e;
    }
}

// Sort each CN's 6 edges ascending -> deterministic order.
__global__ __launch_bounds__(256) void sort_cn(int* __restrict__ cn_edges) {
    int m = blockIdx.x * 256 + threadIdx.x;
    if (m < MC) {
        int v[DC];
        for (int j = 0; j < DC; ++j) v[j] = cn_edges[m * DC + j];
        for (int i = 1; i < DC; ++i) {
            int key = v[i]; int j = i - 1;
            while (j >= 0 && v[j] > key) { v[j + 1] = v[j]; --j; }
            v[j + 1] = key;
        }
        for (int j = 0; j < DC; ++j) cn_edges[m * DC + j] = v[j];
    }
}

// One workgroup per batch element; all E messages live in LDS (48 KB).
// CN update in PRODUCT domain: excl-magnitude via prefix/suffix products of
// T_i = |tanh(mw_i/2)| + 1e-12 (exclusion product == exp(log-sum exclusion)
// of the reference, with ~10x less rounding error than the log path).
// Sign via sign-bit XOR parity (exact, == reference's mod-2 arithmetic).
__global__ __launch_bounds__(TPB, 8) void bp_iter(const float* __restrict__ noise_r,
                                                  const float* __restrict__ ew,
                                                  const int* __restrict__ cn_edges,
                                                  float* __restrict__ out) {
    __shared__ float msg[NE];
    const int b = blockIdx.x;
    const int t = threadIdx.x;

    const float NO   = (float)0.3981071705534972;          // 1/(R*2*10^(EbNo/10))
    const float NSTD = sqrtf((float)(0.3981071705534972 * 0.5));
    const float CLIP = (float)(1.0 - 1e-7);

    // Hoist per-CN edge lists into registers (one-time global read).
    int eidx[MC / TPB][DC];
#pragma unroll
    for (int c = 0; c < MC / TPB; ++c)
#pragma unroll
        for (int j = 0; j < DC; ++j)
            eidx[c][j] = cn_edges[(t + TPB * c) * DC + j];

    float llr[NV / TPB];
    const float* nb = noise_r + (size_t)b * NV;
#pragma unroll
    for (int k = 0; k < NV / TPB; ++k) {
        int n = t + TPB * k;
        float y = 1.0f + NSTD * nb[n];
        float l = (4.0f * y) / NO;
        llr[k] = l;
        msg[3 * n + 0] = l * ew[3 * n + 0];
        msg[3 * n + 1] = l * ew[3 * n + 1];
        msg[3 * n + 2] = l * ew[3 * n + 2];
    }
    __syncthreads();

    for (int it = 0; it < NITER; ++it) {
        // ---- CN update: each thread owns 2 check nodes ----
#pragma unroll
        for (int c = 0; c < MC / TPB; ++c) {
            float T[DC];
            unsigned int sv[DC];
            unsigned int par = 0u;
#pragma unroll
            for (int j = 0; j < DC; ++j) {
                float mw = msg[eidx[c][j]];
                // |tanh(mw/2)| = (1 - e^{-|mw|}) / (1 + e^{-|mw|})
                float u  = __expf(-fabsf(mw));
                float tt = __fdividef(1.0f - u, 1.0f + u);
                T[j] = tt + 1e-12f;                       // matches |t|+eps
                unsigned int sb = __float_as_uint(mw) & 0x80000000u;
                sv[j] = sb;
                par ^= sb;
            }
            // prefix/suffix exclusion products (ascending edge order)
            float pre[DC], suf[DC];
            pre[0] = 1.0f;
#pragma unroll
            for (int j = 1; j < DC; ++j) pre[j] = pre[j - 1] * T[j - 1];
            suf[DC - 1] = 1.0f;
#pragma unroll
            for (int j = DC - 2; j >= 0; --j) suf[j] = suf[j + 1] * T[j + 1];
#pragma unroll
            for (int j = 0; j < DC; ++j) {
                float mag = fminf(pre[j] * suf[j], CLIP);
                // 2*atanh(m) = ln((1+m)/(1-m)) >= 0
                float val = __logf(__fdividef(1.0f + mag, 1.0f - mag));
                unsigned int sgn = par ^ sv[j];           // exclusion parity
                msg[eidx[c][j]] = __uint_as_float(__float_as_uint(val) | sgn);
            }
        }
        __syncthreads();

        // ---- VN update: each thread owns 4 variable nodes ----
        if (it < NITER - 1) {
#pragma unroll
            for (int k = 0; k < NV / TPB; ++k) {
                int n = t + TPB * k;
                float c0 = msg[3 * n + 0];
                float c1 = msg[3 * n + 1];
                float c2 = msg[3 * n + 2];
                float tot = llr[k] + (c0 + c1 + c2);
                msg[3 * n + 0] = (tot - c0) * ew[3 * n + 0];
                msg[3 * n + 1] = (tot - c1) * ew[3 * n + 1];
                msg[3 * n + 2] = (tot - c2) * ew[3 * n + 2];
            }
            __syncthreads();
        } else {
#pragma unroll
            for (int k = 0; k < NV / TPB; ++k) {
                int n = t + TPB * k;
                float c0 = msg[3 * n + 0];
                float c1 = msg[3 * n + 1];
                float c2 = msg[3 * n + 2];
                out[(size_t)b * NV + n] = llr[k] + (c0 + c1 + c2);
            }
        }
    }
}

extern "C" void kernel_launch(void* const* d_in, const int* in_sizes, int n_in,
                              void* d_out, int out_size, void* d_ws, size_t ws_size,
                              hipStream_t stream) {
    const float* noise_r = (const float*)d_in[0];
    // d_in[1] = noise_i (unused by reference)
    const float* ew      = (const float*)d_in[2];
    // d_in[3] = vn_idx: known structure e // 3 (edges contiguous per VN)
    const int*   cn_idx  = (const int*)d_in[4];
    float* out = (float*)d_out;

    int* cn_edges = (int*)d_ws;        // NE ints
    int* cn_cnt   = cn_edges + NE;     // MC ints

    hipMemsetAsync(cn_cnt, 0, MC * sizeof(int), stream);
    build_cn<<<(NE + 255) / 256, 256, 0, stream>>>(cn_idx, cn_edges, cn_cnt);
    sort_cn<<<(MC + 255) / 256, 256, 0, stream>>>(cn_edges);
    bp_iter<<<NB, TPB, 0, stream>>>(noise_r, ew, cn_edges, out);
}